// Round 1
// baseline (2965.334 us; speedup 1.0000x reference)
//
#include <hip/hip_runtime.h>
#include <math.h>

#define HW   96
#define LPIX 9216      // 96*96
#define CDIM 128

static constexpr float kScale = 0.17677669529663687f;  // 1/sqrt(32)

// ---------------------------------------------------------------------------
// conv3x3 (pad 1) + BN-scale + bias + ReLU.  NCHW.
// grid: (36 spatial tiles of 16x16, 16 co-groups of 8, B). block 256.
// ---------------------------------------------------------------------------
template <int CIN>
__global__ __launch_bounds__(256) void conv3x3_bn_relu(
    const float* __restrict__ in, const float* __restrict__ w,
    const float* __restrict__ gamma, const float* __restrict__ beta,
    float* __restrict__ out)
{
    const int tile = blockIdx.x;
    const int cg   = blockIdx.y;
    const int b    = blockIdx.z;
    const int y0   = (tile / 6) * 16;
    const int x0   = (tile % 6) * 16;
    const int tid  = threadIdx.x;
    const int ty   = tid >> 4;
    const int tx   = tid & 15;

    __shared__ float sIn[18 * 20];   // 18x18 tile, padded pitch 20

    float acc[8];
#pragma unroll
    for (int o = 0; o < 8; ++o) acc[o] = 0.f;

    const float* inb = in + ((size_t)b * CIN) * (HW * HW);

    for (int ci = 0; ci < CIN; ++ci) {
        const float* inc = inb + (size_t)ci * (HW * HW);
        for (int i = tid; i < 324; i += 256) {
            int r = i / 18, c = i - r * 18;
            int gy = y0 - 1 + r, gx = x0 - 1 + c;
            float v = 0.f;
            if (gy >= 0 && gy < HW && gx >= 0 && gx < HW) v = inc[gy * HW + gx];
            sIn[r * 20 + c] = v;
        }
        __syncthreads();
        // block-uniform weight indices -> scalar loads
        const float* wp = w + ((size_t)(cg * 8) * CIN + ci) * 9;
#pragma unroll
        for (int ki = 0; ki < 3; ++ki) {
#pragma unroll
            for (int kj = 0; kj < 3; ++kj) {
                float v = sIn[(ty + ki) * 20 + tx + kj];
#pragma unroll
                for (int o = 0; o < 8; ++o)
                    acc[o] = fmaf(v, wp[(size_t)o * CIN * 9 + ki * 3 + kj], acc[o]);
            }
        }
        __syncthreads();
    }

    const int y = y0 + ty, x = x0 + tx;
    const float rs = rsqrtf(1.f + 1e-5f);
#pragma unroll
    for (int o = 0; o < 8; ++o) {
        int co   = cg * 8 + o;
        float sc = gamma[co] * rs;
        float r  = fmaf(acc[o], sc, beta[co]);
        out[(((size_t)b * CDIM + co) * HW + y) * HW + x] = fmaxf(r, 0.f);
    }
}

// ---------------------------------------------------------------------------
// per-pixel 128->128 linear (1x1 conv) + bias.  in/out layout [b, c, l].
// grid: (36 pixel tiles of 256, 4 co-groups of 32, B). block 256.
// ---------------------------------------------------------------------------
__global__ __launch_bounds__(256) void linear128(
    const float* __restrict__ in, const float* __restrict__ w,
    const float* __restrict__ bias, float* __restrict__ out)
{
    const int pt  = blockIdx.x;
    const int cg  = blockIdx.y;
    const int b   = blockIdx.z;
    const int tid = threadIdx.x;
    const int l0  = pt * 256;

    __shared__ float sIn[32 * 256];

    float acc[32];
#pragma unroll
    for (int o = 0; o < 32; ++o) acc[o] = 0.f;

    const float* inb = in + (size_t)b * CDIM * LPIX + l0;

    for (int cc = 0; cc < 128; cc += 32) {
        __syncthreads();
        for (int i = 0; i < 32; ++i)
            sIn[i * 256 + tid] = inb[(size_t)(cc + i) * LPIX + tid];
        __syncthreads();
#pragma unroll
        for (int ii = 0; ii < 32; ii += 8) {
            float v[8];
#pragma unroll
            for (int k = 0; k < 8; ++k) v[k] = sIn[(ii + k) * 256 + tid];
#pragma unroll
            for (int o = 0; o < 32; ++o) {
                const float* wr = w + (size_t)(cg * 32 + o) * 128 + cc + ii;
#pragma unroll
                for (int k = 0; k < 8; ++k) acc[o] = fmaf(v[k], wr[k], acc[o]);
            }
        }
    }
#pragma unroll
    for (int o = 0; o < 32; ++o) {
        int co = cg * 32 + o;
        out[((size_t)b * CDIM + co) * LPIX + l0 + tid] = acc[o] + bias[co];
    }
}

// ---------------------------------------------------------------------------
// attn logits (324x128 per pixel) + bias + scale + softmax over q(9).
// writes A in layout [b, h, p, L, 9].
// grid: (288 pixel tiles of 32, B). block 576 = 36 rows (h,p) x 16 lanes,
// each thread handles 2 pixels.
// ---------------------------------------------------------------------------
__global__ __launch_bounds__(576) void attn_softmax(
    const float* __restrict__ fg, const float* __restrict__ aw,
    const float* __restrict__ ab, float* __restrict__ out)
{
    const int bt  = blockIdx.x;
    const int b   = blockIdx.y;
    const int l0  = bt * 32;
    const int tid = threadIdx.x;
    const int r   = tid >> 4;   // 0..35 = h*9+p
    const int u   = tid & 15;

    __shared__ float sW[324 * 32];
    __shared__ float sF[32 * 36];   // [px][ci-chunk] pitch 36 (conflict-free f4)

    float lg0[9], lg1[9];
#pragma unroll
    for (int q = 0; q < 9; ++q) { lg0[q] = 0.f; lg1[q] = 0.f; }

    for (int cc = 0; cc < 128; cc += 32) {
        __syncthreads();
        for (int i = tid; i < 324 * 32; i += 576)
            sW[i] = aw[(size_t)(i >> 5) * 128 + cc + (i & 31)];
        for (int i = tid; i < 1024; i += 576) {
            int ci = i >> 5, px = i & 31;
            sF[px * 36 + ci] = fg[((size_t)b * CDIM + cc + ci) * LPIX + l0 + px];
        }
        __syncthreads();

        float4 fA[8], fB[8];
#pragma unroll
        for (int k = 0; k < 8; ++k) {
            fA[k] = *(const float4*)&sF[u * 36 + k * 4];
            fB[k] = *(const float4*)&sF[(u + 16) * 36 + k * 4];
        }
        const int obase = r * 9;
#pragma unroll
        for (int q = 0; q < 9; ++q) {
            const float4* wr = (const float4*)&sW[(obase + q) * 32];
            float s0 = 0.f, s1 = 0.f;
#pragma unroll
            for (int k = 0; k < 8; ++k) {
                float4 wv = wr[k];
                s0 += wv.x * fA[k].x + wv.y * fA[k].y + wv.z * fA[k].z + wv.w * fA[k].w;
                s1 += wv.x * fB[k].x + wv.y * fB[k].y + wv.z * fB[k].z + wv.w * fB[k].w;
            }
            lg0[q] += s0;
            lg1[q] += s1;
        }
    }

    const int h = r / 9, p = r - (r / 9) * 9;
    const int obase = r * 9;
    float bs[9];
#pragma unroll
    for (int q = 0; q < 9; ++q) bs[q] = ab[obase + q];

    float* outb = out + (((size_t)(b * 4 + h) * 9 + p) * LPIX) * 9;

    {
        float m = -1e30f;
#pragma unroll
        for (int q = 0; q < 9; ++q) { lg0[q] = (lg0[q] + bs[q]) * kScale; m = fmaxf(m, lg0[q]); }
        float s = 0.f;
#pragma unroll
        for (int q = 0; q < 9; ++q) { lg0[q] = __expf(lg0[q] - m); s += lg0[q]; }
        float inv = 1.f / s;
        float* o0 = outb + (size_t)(l0 + u) * 9;
#pragma unroll
        for (int q = 0; q < 9; ++q) o0[q] = lg0[q] * inv;
    }
    {
        float m = -1e30f;
#pragma unroll
        for (int q = 0; q < 9; ++q) { lg1[q] = (lg1[q] + bs[q]) * kScale; m = fmaxf(m, lg1[q]); }
        float s = 0.f;
#pragma unroll
        for (int q = 0; q < 9; ++q) { lg1[q] = __expf(lg1[q] - m); s += lg1[q]; }
        float inv = 1.f / s;
        float* o1 = outb + (size_t)(l0 + u + 16) * 9;
#pragma unroll
        for (int q = 0; q < 9; ++q) o1[q] = lg1[q] * inv;
    }
}

// ---------------------------------------------------------------------------
// fused einsum + fold: folded[b,c,y,x] = sum_{oy,ox in 5x5} S[oy,ox]*v[c,y+oy-2,x+ox-2]
// with S[oy,ox] = sum over (p,q) with q-k offset == (oy,ox), l'(p) in bounds,
// of A[b,h,p,l'(p),q].
// grid: (288 tiles of 8x4, B). block 128 = 4 heads x (4y x 8x) pixels.
// ---------------------------------------------------------------------------
__global__ __launch_bounds__(128) void attn_fold(
    const float* __restrict__ A, const float* __restrict__ v,
    float* __restrict__ out)
{
    const int tile = blockIdx.x;            // 0..287
    const int b    = blockIdx.y;
    const int y0   = (tile / 12) * 4;
    const int x0   = (tile % 12) * 8;
    const int tid  = threadIdx.x;
    const int h    = tid >> 5;
    const int py   = (tid >> 3) & 3;
    const int px   = tid & 7;

    __shared__ float sV[96 * 132];   // [spatial 8x12][c pitch 132]

    for (int i = tid; i < 96 * 128; i += 128) {
        int c = i / 96, s = i - c * 96;
        int sy = s / 12, sx = s - sy * 12;
        int gy = y0 - 2 + sy, gx = x0 - 2 + sx;
        float val = 0.f;
        if (gy >= 0 && gy < HW && gx >= 0 && gx < HW)
            val = v[(((size_t)b * CDIM + c) * HW + gy) * HW + gx];
        sV[s * 132 + c] = val;
    }
    __syncthreads();

    const int y = y0 + py, x = x0 + px;

    float S[25];
#pragma unroll
    for (int i = 0; i < 25; ++i) S[i] = 0.f;

    const float* Ab = A + ((size_t)(b * 4 + h) * 9) * ((size_t)LPIX * 9);
#pragma unroll
    for (int ki = 0; ki < 3; ++ki) {
        int ly = y + 1 - ki;
        bool vy = (ly >= 0 && ly < HW);
#pragma unroll
        for (int kj = 0; kj < 3; ++kj) {
            int lx = x + 1 - kj;
            if (vy && lx >= 0 && lx < HW) {
                const float* Ap = Ab + ((size_t)(ki * 3 + kj) * LPIX + ly * HW + lx) * 9;
#pragma unroll
                for (int q = 0; q < 9; ++q) {
                    int qi = q / 3, qj = q - qi * 3;
                    S[(qi - ki + 2) * 5 + (qj - kj + 2)] += Ap[q];
                }
            }
        }
    }

    float4 acc[8];
#pragma unroll
    for (int k = 0; k < 8; ++k) acc[k] = make_float4(0.f, 0.f, 0.f, 0.f);

#pragma unroll
    for (int oy = 0; oy < 5; ++oy) {
#pragma unroll
        for (int ox = 0; ox < 5; ++ox) {
            float sc = S[oy * 5 + ox];
            const float4* vr =
                (const float4*)&sV[((py + oy) * 12 + px + ox) * 132 + h * 32];
#pragma unroll
            for (int k = 0; k < 8; ++k) {
                float4 vv = vr[k];
                acc[k].x = fmaf(sc, vv.x, acc[k].x);
                acc[k].y = fmaf(sc, vv.y, acc[k].y);
                acc[k].z = fmaf(sc, vv.z, acc[k].z);
                acc[k].w = fmaf(sc, vv.w, acc[k].w);
            }
        }
    }

    float* ob = out + (((size_t)b * CDIM + h * 32) * HW + y) * HW + x;
#pragma unroll
    for (int k = 0; k < 8; ++k) {
        ob[(size_t)(k * 4 + 0) * HW * HW] = acc[k].x;
        ob[(size_t)(k * 4 + 1) * HW * HW] = acc[k].y;
        ob[(size_t)(k * 4 + 2) * HW * HW] = acc[k].z;
        ob[(size_t)(k * 4 + 3) * HW * HW] = acc[k].w;
    }
}

// ---------------------------------------------------------------------------
extern "C" void kernel_launch(void* const* d_in, const int* in_sizes, int n_in,
                              void* d_out, int out_size, void* d_ws, size_t ws_size,
                              hipStream_t stream)
{
    const float* x    = (const float*)d_in[0];
    const float* fg   = (const float*)d_in[1];
    const float* c1w  = (const float*)d_in[2];
    const float* bn1g = (const float*)d_in[3];
    const float* bn1b = (const float*)d_in[4];
    const float* c2w  = (const float*)d_in[5];
    const float* bn2g = (const float*)d_in[6];
    const float* bn2b = (const float*)d_in[7];
    const float* vw   = (const float*)d_in[8];
    const float* vb   = (const float*)d_in[9];
    const float* aw   = (const float*)d_in[10];
    const float* abv  = (const float*)d_in[11];
    const float* pw   = (const float*)d_in[12];
    const float* pb   = (const float*)d_in[13];
    const float* c3w  = (const float*)d_in[14];
    const float* bn3g = (const float*)d_in[15];
    const float* bn3b = (const float*)d_in[16];
    const float* c4w  = (const float*)d_in[17];
    const float* bn4g = (const float*)d_in[18];
    const float* bn4b = (const float*)d_in[19];

    float* bufA = (float*)d_ws;                    // 9,437,184 floats
    float* bufB = bufA + (size_t)9437184;          // 9,437,184 floats
    float* bufD = bufB + (size_t)9437184;          // 23,887,872 floats (attn)

    dim3 cgrid(36, 16, 8);
    conv3x3_bn_relu<64><<<cgrid, 256, 0, stream>>>(x, c1w, bn1g, bn1b, bufA);
    conv3x3_bn_relu<128><<<cgrid, 256, 0, stream>>>(bufA, c2w, bn2g, bn2b, bufB);
    linear128<<<dim3(36, 4, 8), 256, 0, stream>>>(bufB, vw, vb, bufA);     // v
    attn_softmax<<<dim3(288, 8), 576, 0, stream>>>(fg, aw, abv, bufD);
    attn_fold<<<dim3(288, 8), 128, 0, stream>>>(bufD, bufA, bufB);         // folded
    linear128<<<dim3(36, 4, 8), 256, 0, stream>>>(bufB, pw, pb, bufA);     // proj
    conv3x3_bn_relu<128><<<cgrid, 256, 0, stream>>>(bufA, c3w, bn3g, bn3b, bufB);
    conv3x3_bn_relu<128><<<cgrid, 256, 0, stream>>>(bufB, c4w, bn4g, bn4b, (float*)d_out);
}